// Round 7
// baseline (466.733 us; speedup 1.0000x reference)
//
#include <hip/hip_runtime.h>
#include <hip/hip_bf16.h>

#define D_MODEL 1024
#define NHEAD   16
#define DK      64
#define SEQ     2048
#define BATCH   2

typedef __attribute__((ext_vector_type(8))) short bf16x8;   // 8 bf16 = 4 VGPR
typedef __attribute__((ext_vector_type(4))) float f32x4;

static __device__ __forceinline__ ushort f2bf(float f) {
  union { float f; unsigned u; } x; x.f = f;
  unsigned r = x.u + 0x7FFF + ((x.u >> 16) & 1);   // round-to-nearest-even
  return (ushort)(r >> 16);
}
static __device__ __forceinline__ float bf2f(ushort b) {
  union { unsigned u; float f; } x; x.u = ((unsigned)b) << 16;
  return x.f;
}

// Load one 8-element bf16 chunk from either an fp32 or a bf16 source.
template<bool F32>
static __device__ __forceinline__ bf16x8 load_chunk(const void* base, size_t eoff) {
  if constexpr (F32) {
    const float* p = (const float*)base + eoff;
    float4 a = *(const float4*)p;
    float4 b = *(const float4*)(p + 4);
    bf16x8 o;
    o[0] = (short)f2bf(a.x); o[1] = (short)f2bf(a.y);
    o[2] = (short)f2bf(a.z); o[3] = (short)f2bf(a.w);
    o[4] = (short)f2bf(b.x); o[5] = (short)f2bf(b.y);
    o[6] = (short)f2bf(b.z); o[7] = (short)f2bf(b.w);
    return o;
  } else {
    return *(const bf16x8*)((const ushort*)base + eoff);
  }
}

// ---------------- bf16 MFMA GEMM: C = A @ B^T + bias ----------------
// outScale multiplies (acc+bias) before the write (used to fold the 1/8
// attention score scale into the Q projection).
template<int MODE, bool AF32, bool BF32>
__global__ __launch_bounds__(512) void gemm_bf16(
    const void* __restrict__ A, const void* __restrict__ B,
    const float* __restrict__ bias, void* __restrict__ C,
    int M, int N, int K, float outScale)
{
  __shared__ __align__(16) ushort At[2][128 * 32];
  __shared__ __align__(16) ushort Bt[2][128 * 32];
  const int tid = threadIdx.x;
  const int lane = tid & 63, wave = tid >> 6;
  const int wm = wave >> 1, wn = wave & 1;
  const int m0 = blockIdx.y * 128, n0 = blockIdx.x * 128;
  const int row = tid >> 2, kc = tid & 3;
  const size_t aoff = (size_t)(m0 + row) * K + kc * 8;
  const size_t boff = (size_t)(n0 + row) * K + kc * 8;
  const int lchunk = (kc * 128 + row) * 8;

  bf16x8 ra = load_chunk<AF32>(A, aoff);
  bf16x8 rb = load_chunk<BF32>(B, boff);
  *(bf16x8*)&At[0][lchunk] = ra;
  *(bf16x8*)&Bt[0][lchunk] = rb;
  __syncthreads();

  f32x4 acc[2][4];
  #pragma unroll
  for (int i = 0; i < 2; ++i)
    #pragma unroll
    for (int j = 0; j < 4; ++j) acc[i][j] = (f32x4){0.f, 0.f, 0.f, 0.f};

  for (int t = 0; t < 32; ++t) {
    const int cur = t & 1;
    if (t < 31) {
      ra = load_chunk<AF32>(A, aoff + (size_t)(t + 1) * 32);
      rb = load_chunk<BF32>(B, boff + (size_t)(t + 1) * 32);
    }
    bf16x8 af[2], bfr[4];
    #pragma unroll
    for (int i = 0; i < 2; ++i)
      af[i] = *(const bf16x8*)&At[cur][((lane >> 4) * 128 + wm * 32 + i * 16 + (lane & 15)) * 8];
    #pragma unroll
    for (int j = 0; j < 4; ++j)
      bfr[j] = *(const bf16x8*)&Bt[cur][((lane >> 4) * 128 + wn * 64 + j * 16 + (lane & 15)) * 8];
    __builtin_amdgcn_s_setprio(1);
    #pragma unroll
    for (int i = 0; i < 2; ++i)
      #pragma unroll
      for (int j = 0; j < 4; ++j)
        acc[i][j] = __builtin_amdgcn_mfma_f32_16x16x32_bf16(af[i], bfr[j], acc[i][j], 0, 0, 0);
    __builtin_amdgcn_s_setprio(0);
    if (t < 31) {
      *(bf16x8*)&At[cur ^ 1][lchunk] = ra;
      *(bf16x8*)&Bt[cur ^ 1][lchunk] = rb;
    }
    __syncthreads();
  }

  #pragma unroll
  for (int i = 0; i < 2; ++i) {
    #pragma unroll
    for (int j = 0; j < 4; ++j) {
      #pragma unroll
      for (int r = 0; r < 4; ++r) {
        int m = m0 + wm * 32 + i * 16 + (lane >> 4) * 4 + r;
        int n = n0 + wn * 64 + j * 16 + (lane & 15);
        float val = (acc[i][j][r] + bias[n]) * outScale;
        if (MODE == 0) {
          ((float*)C)[(size_t)m * N + n] = val;
        } else {
          int b = m >> 11, s = m & (SEQ - 1);
          int h = n >> 6,  d = n & (DK - 1);
          if (MODE == 1)
            ((ushort*)C)[((size_t)(b * NHEAD + h) * SEQ + s) * DK + d] = f2bf(val);
          else
            ((ushort*)C)[((size_t)(b * NHEAD + h) * DK + d) * SEQ + s] = f2bf(val);
        }
      }
    }
  }
}

// ---------------- MFMA attention (swapped QK^T, store/load de-interleave) ----------------
// One block = 16 q-rows of one (b,h); 512 threads / 8 waves; wave w owns keys
// [w*256, w*256+256). Q is PRE-SCALED by 1/8 in its projection.
// Phase order: QK^T+exp+sP -> sums -> PV (pure loads+MFMA, 4-deep V prefetch)
// -> attn store loop (pure stores, fire-and-forget) -> ctx reduce.
// Rationale: stores share vmcnt with loads; interleaving them makes every
// MFMA's vmcnt wait also drain older stores (R5/R6 evidence).
__global__ __launch_bounds__(512) void attn_mfma(
    const ushort* __restrict__ Qh, const ushort* __restrict__ Kh,
    const ushort* __restrict__ Vt, float* __restrict__ attn,
    ushort* __restrict__ ctxb)
{
  __shared__ __align__(16) ushort sP[16 * SEQ];   // 64 KB bf16 p=exp(s)
  __shared__ float sRed[8][16];
  __shared__ float sSum[16];

  const int tid = threadIdx.x;
  const int lane = tid & 63, wave = tid >> 6;     // 8 waves
  const int l16 = lane & 15, lq = lane >> 4;
  // XCD swizzle: 4096 blocks = 8 XCDs x 512; 4 consecutive bh per XCD.
  const int bid  = blockIdx.x;
  const int sbid = (bid & 7) * 512 + (bid >> 3);
  const int bh = sbid >> 7;
  const int q0 = (sbid & 127) * 16;
  const ushort* Qp = Qh + ((size_t)bh * SEQ + q0) * DK;
  const ushort* Kp = Kh + (size_t)bh * SEQ * DK;
  const ushort* Vp = Vt + (size_t)bh * DK * SEQ;

  // Q fragments (B-operand of swapped MFMA): row-space = q = l16
  bf16x8 bq0 = *(const bf16x8*)(Qp + l16 * DK + lq * 8);
  bf16x8 bq1 = *(const bf16x8*)(Qp + l16 * DK + 32 + lq * 8);

  // ---- Phase 1: swapped QK^T: acc = mfma(K_frag, Q_frag) ----
  // D[row-space = keys][col-space = q]: lane holds q=l16, keys = base+lq*4+r
  // -> 4 consecutive keys per (lane, ni) -> packed ds_write_b64.
  bf16x8 kb[2][8];
  const ushort* kbase = Kp + (size_t)(wave * 256 + l16) * DK + lq * 8;
  #pragma unroll
  for (int ni = 0; ni < 4; ++ni) {
    kb[0][2 * ni]     = *(const bf16x8*)(kbase + (size_t)ni * 16 * DK);
    kb[0][2 * ni + 1] = *(const bf16x8*)(kbase + (size_t)ni * 16 * DK + 32);
  }
  float lsum = 0.f;                               // row sum for q = l16
  const int swz = l16 & 7;
  #pragma unroll
  for (int it = 0; it < 4; ++it) {
    const int cb = it & 1;
    if (it < 3) {
      const ushort* kn = kbase + (size_t)(it + 1) * 64 * DK;
      #pragma unroll
      for (int ni = 0; ni < 4; ++ni) {
        kb[cb ^ 1][2 * ni]     = *(const bf16x8*)(kn + (size_t)ni * 16 * DK);
        kb[cb ^ 1][2 * ni + 1] = *(const bf16x8*)(kn + (size_t)ni * 16 * DK + 32);
      }
    }
    f32x4 acc[4];
    __builtin_amdgcn_s_setprio(1);
    #pragma unroll
    for (int ni = 0; ni < 4; ++ni) {
      acc[ni] = (f32x4){0.f, 0.f, 0.f, 0.f};
      acc[ni] = __builtin_amdgcn_mfma_f32_16x16x32_bf16(kb[cb][2 * ni],     bq0, acc[ni], 0, 0, 0);
      acc[ni] = __builtin_amdgcn_mfma_f32_16x16x32_bf16(kb[cb][2 * ni + 1], bq1, acc[ni], 0, 0, 0);
    }
    __builtin_amdgcn_s_setprio(0);
    const int key0 = wave * 256 + it * 64;
    #pragma unroll
    for (int ni = 0; ni < 4; ++ni) {
      float p0 = __expf(acc[ni][0]);
      float p1 = __expf(acc[ni][1]);
      float p2 = __expf(acc[ni][2]);
      float p3 = __expf(acc[ni][3]);
      lsum += (p0 + p1) + (p2 + p3);
      ushort4 pk;
      pk.x = f2bf(p0); pk.y = f2bf(p1); pk.z = f2bf(p2); pk.w = f2bf(p3);
      int col = key0 + ni * 16 + lq * 4;           // 4 consecutive keys
      int chunk = col >> 3;
      *(ushort4*)&sP[l16 * SEQ + ((chunk ^ swz) << 3) + (col & 7)] = pk;
    }
  }

  // ---- row-sum reduce: lanes with same l16 hold partial for q=l16 ----
  lsum += __shfl_xor(lsum, 16);
  lsum += __shfl_xor(lsum, 32);
  if (lane < 16) sRed[wave][lane] = lsum;
  __syncthreads();
  if (tid < 16) {
    float s = 0.f;
    #pragma unroll
    for (int w = 0; w < 8; ++w) s += sRed[w][tid];
    sSum[tid] = s;
  }
  __syncthreads();

  // ---- Phase 2: PV only (pure loads + MFMA, no stores). ----
  // Wave covers keys [wave*256,+256) in 8 iterations; V 4-deep prefetch
  // (distance 3), pa (LDS) 2-deep.
  f32x4 cacc[4];
  #pragma unroll
  for (int ni = 0; ni < 4; ++ni) cacc[ni] = (f32x4){0.f, 0.f, 0.f, 0.f};

  const ushort* sProw = sP + l16 * SEQ;            // P row q=l16 (A-frag)
  const ushort* vbase = Vp + (size_t)l16 * SEQ + wave * 256 + lq * 8;
  bf16x8 vb[4][4];
  #pragma unroll
  for (int s = 0; s < 3; ++s)
    #pragma unroll
    for (int ni = 0; ni < 4; ++ni)
      vb[s][ni] = *(const bf16x8*)(vbase + (size_t)ni * 16 * SEQ + s * 32);
  bf16x8 pa[2];
  pa[0] = *(const bf16x8*)&sProw[((wave * 32 + lq) ^ swz) * 8];

  #pragma unroll
  for (int ks = 0; ks < 8; ++ks) {
    // prefetch V for ks+3 into a slot not in use this iteration
    if (ks < 5) {
      #pragma unroll
      for (int ni = 0; ni < 4; ++ni)
        vb[(ks + 3) & 3][ni] = *(const bf16x8*)(vbase + (size_t)ni * 16 * SEQ + (ks + 3) * 32);
    }
    if (ks < 7)
      pa[(ks + 1) & 1] = *(const bf16x8*)&sProw[((wave * 32 + (ks + 1) * 4 + lq) ^ swz) * 8];
    __builtin_amdgcn_s_setprio(1);
    #pragma unroll
    for (int ni = 0; ni < 4; ++ni)
      cacc[ni] = __builtin_amdgcn_mfma_f32_16x16x32_bf16(pa[ks & 1], vb[ks & 3][ni], cacc[ni], 0, 0, 0);
    __builtin_amdgcn_s_setprio(0);
  }

  // ---- Phase 3: attn store loop (pure stores, fire-and-forget) ----
  {
    const int wrow = tid >> 5, l32 = tid & 31;
    const float invw = 1.0f / sSum[wrow];
    const int wswz = wrow & 7;
    const ushort* rowp = sP + wrow * SEQ;
    float* attnRow = attn + ((size_t)(bh * SEQ + q0 + wrow)) * SEQ;
    #pragma unroll
    for (int i = 0; i < 8; ++i) {
      int ch = l32 + i * 32;
      bf16x8 pv = *(const bf16x8*)&rowp[(ch ^ wswz) * 8];
      float4 o0, o1;
      o0.x = bf2f((ushort)pv[0]) * invw; o0.y = bf2f((ushort)pv[1]) * invw;
      o0.z = bf2f((ushort)pv[2]) * invw; o0.w = bf2f((ushort)pv[3]) * invw;
      o1.x = bf2f((ushort)pv[4]) * invw; o1.y = bf2f((ushort)pv[5]) * invw;
      o1.z = bf2f((ushort)pv[6]) * invw; o1.w = bf2f((ushort)pv[7]) * invw;
      *(float4*)&attnRow[ch * 8] = o0;
      *(float4*)&attnRow[ch * 8 + 4] = o1;
    }
  }

  // ---- Phase 4: cross-wave reduce (reuse sP as f32 scratch) + ctx bf16 ----
  __syncthreads();   // all LDS reads of sP done -> safe to overwrite
  float* sC = (float*)sP;   // [8][16][64] = 32 KB
  #pragma unroll
  for (int ni = 0; ni < 4; ++ni)
    #pragma unroll
    for (int r = 0; r < 4; ++r)
      sC[wave * 1024 + (lq * 4 + r) * 64 + ni * 16 + l16] = cacc[ni][r];
  __syncthreads();
  if (tid < 256) {
    const int qq = tid >> 4, dv = (tid & 15) * 4;
    float sx = 0.f, sy = 0.f, sz = 0.f, sw = 0.f;
    #pragma unroll
    for (int w = 0; w < 8; ++w) {
      float4 t = *(float4*)&sC[w * 1024 + qq * 64 + dv];
      sx += t.x; sy += t.y; sz += t.z; sw += t.w;
    }
    float iv = 1.0f / sSum[qq];
    ushort4 ob;
    ob.x = f2bf(sx * iv);
    ob.y = f2bf(sy * iv);
    ob.z = f2bf(sz * iv);
    ob.w = f2bf(sw * iv);
    const int bb = bh >> 4, hh = bh & 15;
    *(ushort4*)(ctxb + ((size_t)(bb * SEQ + q0 + qq)) * D_MODEL + hh * DK + dv) = ob;
  }
}

extern "C" void kernel_launch(void* const* d_in, const int* in_sizes, int n_in,
                              void* d_out, int out_size, void* d_ws, size_t ws_size,
                              hipStream_t stream)
{
  const float* q  = (const float*)d_in[0];
  const float* k  = (const float*)d_in[1];
  const float* v  = (const float*)d_in[2];
  const float* Wq = (const float*)d_in[3];
  const float* bq = (const float*)d_in[4];
  const float* Wk = (const float*)d_in[5];
  const float* bk = (const float*)d_in[6];
  const float* Wv = (const float*)d_in[7];
  const float* bv = (const float*)d_in[8];
  const float* Wo = (const float*)d_in[9];
  const float* bo = (const float*)d_in[10];

  float* out  = (float*)d_out;
  float* attn = out + (size_t)BATCH * SEQ * D_MODEL;

  const size_t XEL = (size_t)BATCH * SEQ * D_MODEL;  // 4 Mi elems
  ushort* Qhb  = (ushort*)d_ws;
  ushort* Khb  = Qhb + XEL;
  ushort* Vtb  = Khb + XEL;
  ushort* ctxb = Vtb + XEL;   // 32 MiB total

  const int M = BATCH * SEQ;
  dim3 gg(D_MODEL / 128, M / 128);   // (8, 32) = 256 blocks
  // Q projection carries the 1/8 attention scale (exact: exponent shift).
  gemm_bf16<1, true, true><<<gg, 512, 0, stream>>>(q, Wq, bq, Qhb, M, D_MODEL, D_MODEL, 0.125f);
  gemm_bf16<1, true, true><<<gg, 512, 0, stream>>>(k, Wk, bk, Khb, M, D_MODEL, D_MODEL, 1.0f);
  gemm_bf16<2, true, true><<<gg, 512, 0, stream>>>(v, Wv, bv, Vtb, M, D_MODEL, D_MODEL, 1.0f);

  attn_mfma<<<dim3(BATCH * NHEAD * SEQ / 16), 512, 0, stream>>>(Qhb, Khb, Vtb, attn, ctxb);

  gemm_bf16<0, false, true><<<gg, 512, 0, stream>>>(ctxb, Wo, bo, out, M, D_MODEL, D_MODEL, 1.0f);
}